// Round 2
// baseline (49.965 us; speedup 1.0000x reference)
//
#include <hip/hip_runtime.h>

#define DIM 256

// ---------------- Kernel 1: per-sample prefix scan of chunk sizes ----------
// One block per sample (512 threads). Produces, for every (b, j) slot:
//   row0s[b*P+j]  = global flat row index of chunk start (or -1 if j>=n_peaks[b])
//   nrowss[b*P+j] = chunk length in rows (0 if invalid)
__global__ __launch_bounds__(512) void scan_kernel(
    const int* __restrict__ chunk_size,
    const int* __restrict__ n_peaks,
    int* __restrict__ row0s,
    int* __restrict__ nrowss,
    int B, int L, int P)
{
    const int b = blockIdx.x;
    const int t = threadIdx.x;

    const int np = n_peaks[b];
    int c0 = 0;
    for (int bb = 0; bb < b; ++bb) c0 += n_peaks[bb] + 1;

    __shared__ int s[512];
    const int v = (t < np) ? chunk_size[c0 + t] : 0;
    s[t] = v;
    __syncthreads();
    // Hillis-Steele inclusive scan over 512 elements
    for (int off = 1; off < 512; off <<= 1) {
        int tv = (t >= off) ? s[t - off] : 0;
        __syncthreads();
        s[t] += tv;
        __syncthreads();
    }
    if (t < P) {
        const bool valid = t < np;
        const int excl = (t == 0) ? 0 : s[t - 1];   // exclusive prefix
        row0s[b * P + t]  = valid ? (b * L + excl) : -1;
        nrowss[b * P + t] = valid ? v : 0;
    }
}

// ---------------- Kernel 2: streaming chunk sum ----------------------------
__global__ __launch_bounds__(256) void splitpool_kernel(
    const float* __restrict__ x,
    const int* __restrict__ row0s,
    const int* __restrict__ nrowss,
    float* __restrict__ out)
{
    const int blk = blockIdx.x;
    const int tid = threadIdx.x;

    float4* out4 = (float4*)(out + (size_t)blk * DIM);

    const int row0 = row0s[blk];
    if (row0 < 0) {
        if (tid < DIM / 4) out4[tid] = make_float4(0.f, 0.f, 0.f, 0.f);
        return;
    }
    const int nrows = nrowss[blk];

    // 4 waves; wave w takes rows w, w+4, ... ; lane l owns float4 [4l,4l+4)
    const int wave = tid >> 6;
    const int lane = tid & 63;
    const float4* xp = (const float4*)x + (size_t)row0 * (DIM / 4) + lane;

    float4 a0 = make_float4(0.f, 0.f, 0.f, 0.f);
    float4 a1 = make_float4(0.f, 0.f, 0.f, 0.f);
    int r = wave;
    for (; r + 4 < nrows; r += 8) {
        float4 v0 = xp[(size_t)r * (DIM / 4)];
        float4 v1 = xp[(size_t)(r + 4) * (DIM / 4)];
        a0.x += v0.x; a0.y += v0.y; a0.z += v0.z; a0.w += v0.w;
        a1.x += v1.x; a1.y += v1.y; a1.z += v1.z; a1.w += v1.w;
    }
    if (r < nrows) {
        float4 v0 = xp[(size_t)r * (DIM / 4)];
        a0.x += v0.x; a0.y += v0.y; a0.z += v0.z; a0.w += v0.w;
    }
    a0.x += a1.x; a0.y += a1.y; a0.z += a1.z; a0.w += a1.w;

    __shared__ float4 fred[256];
    fred[tid] = a0;
    __syncthreads();
    if (tid < 64) {
        float4 a  = fred[tid];
        float4 b1 = fred[tid + 64];
        float4 c  = fred[tid + 128];
        float4 d  = fred[tid + 192];
        a.x += b1.x + c.x + d.x;
        a.y += b1.y + c.y + d.y;
        a.z += b1.z + c.z + d.z;
        a.w += b1.w + c.w + d.w;
        out4[tid] = a;
    }
}

// ---------------- Fallback single-kernel path (ws too small) ---------------
__global__ __launch_bounds__(256) void splitpool_fallback(
    const float* __restrict__ x,
    const int* __restrict__ chunk_size,
    const int* __restrict__ n_peaks,
    float* __restrict__ out,
    int B, int L, int P)
{
    const int blk = blockIdx.x;
    const int b   = blk / P;
    const int j   = blk % P;
    const int tid = threadIdx.x;

    float4* out4 = (float4*)(out + (size_t)blk * DIM);

    const int np = n_peaks[b];
    if (j >= np) {
        if (tid < DIM / 4) out4[tid] = make_float4(0.f, 0.f, 0.f, 0.f);
        return;
    }
    int c0 = 0;
    for (int bb = 0; bb < b; ++bb) c0 += n_peaks[bb] + 1;

    __shared__ int ired[256];
    int partial = 0;
    for (int k = tid; k < j; k += 256) partial += chunk_size[c0 + k];
    ired[tid] = partial;
    __syncthreads();
    #pragma unroll
    for (int s = 128; s > 0; s >>= 1) {
        if (tid < s) ired[tid] += ired[tid + s];
        __syncthreads();
    }
    const int prefix = ired[0];
    const int nrows  = chunk_size[c0 + j];
    const size_t row0 = (size_t)b * (size_t)L + (size_t)prefix;

    const int wave = tid >> 6;
    const int lane = tid & 63;
    const float4* xp = (const float4*)(x + row0 * DIM) + lane;

    float4 acc = make_float4(0.f, 0.f, 0.f, 0.f);
    for (int r = wave; r < nrows; r += 4) {
        float4 v = xp[(size_t)r * (DIM / 4)];
        acc.x += v.x; acc.y += v.y; acc.z += v.z; acc.w += v.w;
    }
    __shared__ float4 fred[256];
    fred[tid] = acc;
    __syncthreads();
    if (tid < 64) {
        float4 a  = fred[tid];
        float4 b1 = fred[tid + 64];
        float4 c  = fred[tid + 128];
        float4 d  = fred[tid + 192];
        a.x += b1.x + c.x + d.x;
        a.y += b1.y + c.y + d.y;
        a.z += b1.z + c.z + d.z;
        a.w += b1.w + c.w + d.w;
        out4[tid] = a;
    }
}

extern "C" void kernel_launch(void* const* d_in, const int* in_sizes, int n_in,
                              void* d_out, int out_size, void* d_ws, size_t ws_size,
                              hipStream_t stream) {
    const float* x  = (const float*)d_in[0];
    const int*   cs = (const int*)d_in[1];
    const int*   np = (const int*)d_in[2];
    float*       out = (float*)d_out;

    const int B = in_sizes[2];
    const int P = out_size / (B * DIM);
    const int L = in_sizes[0] / (B * DIM);
    const int slots = B * P;

    if (ws_size >= (size_t)(2 * slots) * sizeof(int)) {
        int* row0s  = (int*)d_ws;
        int* nrowss = row0s + slots;
        scan_kernel<<<dim3(B), 512, 0, stream>>>(cs, np, row0s, nrowss, B, L, P);
        splitpool_kernel<<<dim3(slots), 256, 0, stream>>>(x, row0s, nrowss, out);
    } else {
        splitpool_fallback<<<dim3(slots), 256, 0, stream>>>(x, cs, np, out, B, L, P);
    }
}

// Round 3
// 48.112 us; speedup vs baseline: 1.0385x; 1.0385x over previous
//
#include <hip/hip_runtime.h>

#define DIM 256

// One 64-lane wave per output slot (b, j). No LDS, no barriers.
// Wave computes its chunk-offset prefix via coalesced strided reads of
// chunk_size + a 6-step shfl_xor butterfly, then streams its contiguous
// chunk (~85-110 rows x 1KB) with a 4-deep unrolled accumulator loop.
__global__ __launch_bounds__(256) void splitpool_wave_kernel(
    const float* __restrict__ x,
    const int* __restrict__ chunk_size,
    const int* __restrict__ n_peaks,
    float* __restrict__ out,
    int B, int L, int P, int slots)
{
    const int tid  = threadIdx.x;
    const int wave = tid >> 6;
    const int lane = tid & 63;
    const int slot = blockIdx.x * 4 + wave;
    if (slot >= slots) return;

    const int b = slot / P;
    const int j = slot - b * P;

    float4* out4 = (float4*)out + (size_t)slot * (DIM / 4) + lane;

    const int np = n_peaks[b];
    if (j >= np) {
        // invalid slot: zero (d_out poisoned once, never re-poisoned)
        *out4 = make_float4(0.f, 0.f, 0.f, 0.f);
        return;
    }

    // first chunk index of sample b
    int c0 = 0;
    for (int bb = 0; bb < b; ++bb) c0 += n_peaks[bb] + 1;

    // prefix = sum_{k<j} chunk_size[c0+k], wave-parallel (L2-hot reads)
    int partial = 0;
    for (int k = lane; k < j; k += 64) partial += chunk_size[c0 + k];
    #pragma unroll
    for (int m = 32; m >= 1; m >>= 1) partial += __shfl_xor(partial, m, 64);
    const int prefix = partial;
    const int nrows  = chunk_size[c0 + j];   // broadcast load

    const float4* xp = (const float4*)x
                     + ((size_t)b * (size_t)L + (size_t)prefix) * (DIM / 4)
                     + lane;

    float4 a0 = make_float4(0.f, 0.f, 0.f, 0.f);
    float4 a1 = make_float4(0.f, 0.f, 0.f, 0.f);
    float4 a2 = make_float4(0.f, 0.f, 0.f, 0.f);
    float4 a3 = make_float4(0.f, 0.f, 0.f, 0.f);

    int r = 0;
    for (; r + 3 < nrows; r += 4) {
        float4 v0 = xp[(size_t)(r + 0) * (DIM / 4)];
        float4 v1 = xp[(size_t)(r + 1) * (DIM / 4)];
        float4 v2 = xp[(size_t)(r + 2) * (DIM / 4)];
        float4 v3 = xp[(size_t)(r + 3) * (DIM / 4)];
        a0.x += v0.x; a0.y += v0.y; a0.z += v0.z; a0.w += v0.w;
        a1.x += v1.x; a1.y += v1.y; a1.z += v1.z; a1.w += v1.w;
        a2.x += v2.x; a2.y += v2.y; a2.z += v2.z; a2.w += v2.w;
        a3.x += v3.x; a3.y += v3.y; a3.z += v3.z; a3.w += v3.w;
    }
    for (; r < nrows; ++r) {
        float4 v0 = xp[(size_t)r * (DIM / 4)];
        a0.x += v0.x; a0.y += v0.y; a0.z += v0.z; a0.w += v0.w;
    }

    a0.x += a1.x + a2.x + a3.x;
    a0.y += a1.y + a2.y + a3.y;
    a0.z += a1.z + a2.z + a3.z;
    a0.w += a1.w + a2.w + a3.w;

    *out4 = a0;   // 64 lanes x 16B = coalesced 1KB store
}

extern "C" void kernel_launch(void* const* d_in, const int* in_sizes, int n_in,
                              void* d_out, int out_size, void* d_ws, size_t ws_size,
                              hipStream_t stream) {
    const float* x  = (const float*)d_in[0];
    const int*   cs = (const int*)d_in[1];
    const int*   np = (const int*)d_in[2];
    float*       out = (float*)d_out;

    const int B = in_sizes[2];
    const int P = out_size / (B * DIM);
    const int L = in_sizes[0] / (B * DIM);
    const int slots = B * P;

    const int blocks = (slots + 3) / 4;   // 4 waves per 256-thread block
    splitpool_wave_kernel<<<dim3(blocks), 256, 0, stream>>>(
        x, cs, np, out, B, L, P, slots);
}

// Round 4
// 45.376 us; speedup vs baseline: 1.1011x; 1.0603x over previous
//
#include <hip/hip_runtime.h>

#define DIM 256

// One 256-thread block per output slot (b, j). 4 waves split the chunk's rows
// round-robin (stride 4). Prefix offset computed redundantly per-wave via
// shfl butterfly (no LDS, no barriers); single __syncthreads in the epilogue.
__global__ __launch_bounds__(256) void splitpool_kernel(
    const float* __restrict__ x,
    const int* __restrict__ chunk_size,
    const int* __restrict__ n_peaks,
    float* __restrict__ out,
    int B, int L, int P)
{
    const int blk  = blockIdx.x;
    const int b    = blk / P;
    const int j    = blk - b * P;
    const int tid  = threadIdx.x;
    const int wave = tid >> 6;
    const int lane = tid & 63;

    float4* out4 = (float4*)(out + (size_t)blk * DIM);

    const int np = n_peaks[b];
    if (j >= np) {
        // invalid slot: zero (d_out poisoned once, never re-poisoned)
        if (tid < DIM / 4) out4[tid] = make_float4(0.f, 0.f, 0.f, 0.f);
        return;
    }

    // first chunk index of sample b (8 scalar L2-hot loads max)
    int c0 = 0;
    for (int bb = 0; bb < b; ++bb) c0 += n_peaks[bb] + 1;

    // prefix = sum_{k<j} chunk_size[c0+k], computed redundantly by each wave:
    // coalesced strided reads (L2-hot) + 6-step butterfly. No barriers.
    int partial = 0;
    for (int k = lane; k < j; k += 64) partial += chunk_size[c0 + k];
    #pragma unroll
    for (int m = 32; m >= 1; m >>= 1) partial += __shfl_xor(partial, m, 64);
    const int prefix = partial;
    const int nrows  = chunk_size[c0 + j];   // broadcast load

    const float4* xp = (const float4*)x
                     + ((size_t)b * (size_t)L + (size_t)prefix) * (DIM / 4)
                     + lane;

    // wave w takes rows w, w+4, w+8, ...; 4-deep unroll = 4 loads in flight
    float4 a0 = make_float4(0.f, 0.f, 0.f, 0.f);
    float4 a1 = make_float4(0.f, 0.f, 0.f, 0.f);
    float4 a2 = make_float4(0.f, 0.f, 0.f, 0.f);
    float4 a3 = make_float4(0.f, 0.f, 0.f, 0.f);

    int r = wave;
    for (; r + 12 < nrows; r += 16) {
        float4 v0 = xp[(size_t)(r + 0)  * (DIM / 4)];
        float4 v1 = xp[(size_t)(r + 4)  * (DIM / 4)];
        float4 v2 = xp[(size_t)(r + 8)  * (DIM / 4)];
        float4 v3 = xp[(size_t)(r + 12) * (DIM / 4)];
        a0.x += v0.x; a0.y += v0.y; a0.z += v0.z; a0.w += v0.w;
        a1.x += v1.x; a1.y += v1.y; a1.z += v1.z; a1.w += v1.w;
        a2.x += v2.x; a2.y += v2.y; a2.z += v2.z; a2.w += v2.w;
        a3.x += v3.x; a3.y += v3.y; a3.z += v3.z; a3.w += v3.w;
    }
    for (; r < nrows; r += 4) {
        float4 v0 = xp[(size_t)r * (DIM / 4)];
        a0.x += v0.x; a0.y += v0.y; a0.z += v0.z; a0.w += v0.w;
    }
    a0.x += a1.x + a2.x + a3.x;
    a0.y += a1.y + a2.y + a3.y;
    a0.z += a1.z + a2.z + a3.z;
    a0.w += a1.w + a2.w + a3.w;

    // single-barrier cross-wave reduction
    __shared__ float4 fred[256];
    fred[tid] = a0;
    __syncthreads();
    if (tid < 64) {
        float4 a  = fred[tid];
        float4 b1 = fred[tid + 64];
        float4 c  = fred[tid + 128];
        float4 d  = fred[tid + 192];
        a.x += b1.x + c.x + d.x;
        a.y += b1.y + c.y + d.y;
        a.z += b1.z + c.z + d.z;
        a.w += b1.w + c.w + d.w;
        out4[tid] = a;
    }
}

extern "C" void kernel_launch(void* const* d_in, const int* in_sizes, int n_in,
                              void* d_out, int out_size, void* d_ws, size_t ws_size,
                              hipStream_t stream) {
    const float* x  = (const float*)d_in[0];
    const int*   cs = (const int*)d_in[1];
    const int*   np = (const int*)d_in[2];
    float*       out = (float*)d_out;

    const int B = in_sizes[2];
    const int P = out_size / (B * DIM);
    const int L = in_sizes[0] / (B * DIM);

    splitpool_kernel<<<dim3(B * P), 256, 0, stream>>>(x, cs, np, out, B, L, P);
}